// Round 8
// baseline (12378.683 us; speedup 1.0000x reference)
//
#include <hip/hip_runtime.h>
#include <stdint.h>

typedef __attribute__((ext_vector_type(8))) short short8;
typedef __attribute__((ext_vector_type(4))) float f32x4;
typedef unsigned long long u64;

constexpr int cB = 32, cT = 512, cD = 512, cH = 512;
constexpr int cKI = 6 * cH;   // 3072
constexpr int NWG = 32;
constexpr int THR = 320;
constexpr int LDW = 40;       // gemm LDS row pitch (shorts)
constexpr int HP  = 520;      // rec LDS row pitch (shorts)
constexpr int RNG = 3;        // pi prefetch ring depth
constexpr int NCHK = 8192;    // chunks per h slot: 32 b x 256 col-pairs
constexpr int MAXK = 26;      // ceil(8192/320)

__device__ __forceinline__ float bf2f(unsigned short u) {
  union { unsigned int i; float f; } x; x.i = ((unsigned int)u) << 16; return x.f;
}
__device__ __forceinline__ unsigned short f2bf(float f) {
  union { float f; unsigned int i; } x; x.f = f;
  return (unsigned short)((x.i + 0x7fffu + ((x.i >> 16) & 1u)) >> 16);
}
__device__ __forceinline__ float sigm(float v) { return 1.0f / (1.0f + __expf(-v)); }
__device__ __forceinline__ float tanh_f(float v) { return 2.0f / (1.0f + __expf(-2.0f * v)) - 1.0f; }

// ---------------- Phase 1: pi[t][k][b] = x[b][t][:] . Wi[k][:] + bi[k] ----------------
__global__ __launch_bounds__(256) void gemm_pi(
    const float* __restrict__ x,    // [B][T][D] fp32
    const float* __restrict__ Wi,   // [6H][D] fp32
    const float* __restrict__ bi,   // [6H] fp32
    unsigned short* __restrict__ pi)// [T][6H][B] bf16
{
  __shared__ __align__(16) unsigned short Ai[128 * LDW];
  __shared__ __align__(16) unsigned short Bi[128 * LDW];

  const int tid = threadIdx.x;
  const int lane = tid & 63;
  const int w = tid >> 6;
  const int wm = w & 1, wn = w >> 1;
  const int k0 = blockIdx.x * 128;
  const int n0 = blockIdx.y * 128;   // n = t*32 + b

  f32x4 acc[4][4];
  #pragma unroll
  for (int i = 0; i < 4; i++)
    #pragma unroll
    for (int j = 0; j < 4; j++) acc[i][j] = (f32x4){0.f, 0.f, 0.f, 0.f};

  for (int kk = 0; kk < cD; kk += 32) {
    __syncthreads();
    #pragma unroll
    for (int it = 0; it < 4; it++) {
      int idx = tid + it * 256;
      int r = idx >> 3, ch = idx & 7;
      int na = n0 + r;
      int bb = na & 31, tt = na >> 5;
      float4 va = *(const float4*)(x + ((size_t)bb * cT + tt) * cD + kk + ch * 4);
      ushort4 pa; pa.x = f2bf(va.x); pa.y = f2bf(va.y); pa.z = f2bf(va.z); pa.w = f2bf(va.w);
      *(ushort4*)(Ai + r * LDW + ch * 4) = pa;
      float4 vb = *(const float4*)(Wi + (size_t)(k0 + r) * cD + kk + ch * 4);
      ushort4 pb; pb.x = f2bf(vb.x); pb.y = f2bf(vb.y); pb.z = f2bf(vb.z); pb.w = f2bf(vb.w);
      *(ushort4*)(Bi + r * LDW + ch * 4) = pb;
    }
    __syncthreads();

    short8 af[4], bfr[4];
    const int q = lane >> 4;
    #pragma unroll
    for (int mi = 0; mi < 4; mi++) {
      int m = wm * 64 + mi * 16 + (lane & 15);
      af[mi] = *(const short8*)(Ai + m * LDW + q * 8);
    }
    #pragma unroll
    for (int ni = 0; ni < 4; ni++) {
      int n = wn * 64 + ni * 16 + (lane & 15);
      bfr[ni] = *(const short8*)(Bi + n * LDW + q * 8);
    }
    #pragma unroll
    for (int mi = 0; mi < 4; mi++)
      #pragma unroll
      for (int ni = 0; ni < 4; ni++)
        acc[mi][ni] = __builtin_amdgcn_mfma_f32_16x16x32_bf16(af[mi], bfr[ni], acc[mi][ni], 0, 0, 0);
  }

  #pragma unroll
  for (int ni = 0; ni < 4; ni++) {
    int kl = wn * 64 + ni * 16 + (lane & 15);
    float bv = bi[k0 + kl];
    #pragma unroll
    for (int mi = 0; mi < 4; mi++) {
      int nl = wm * 64 + mi * 16 + (lane >> 4) * 4;
      int nb = n0 + nl;
      int b0 = nb & 31, tt = nb >> 5;
      f32x4 a = acc[mi][ni];
      unsigned short v0 = f2bf(a.x + bv), v1 = f2bf(a.y + bv);
      unsigned short v2 = f2bf(a.z + bv), v3 = f2bf(a.w + bv);
      uint2 pv; pv.x = (unsigned)v0 | ((unsigned)v1 << 16);
      pv.y = (unsigned)v2 | ((unsigned)v3 << 16);
      *(uint2*)(pi + ((size_t)tt * cKI + k0 + kl) * cB + b0) = pv;
    }
  }
}

// ---------------- Phase 2: persistent scan, dataflow chunk exchange ----------------
// h exchanged as self-validating 8B chunks {seq:32 | h1:16 | h0:16} via agent-relaxed
// atomics. No grid barrier, no flags. 2-slot ping-pong (race-free by dataflow chain).
__global__ __launch_bounds__(THR, 1) void lstm_rec(
    const unsigned short* __restrict__ pi,   // [T][6H][B] bf16
    const float* __restrict__ Ws,            // [5H][H] fp32
    const float* __restrict__ bs,            // [5H] fp32
    const int* __restrict__ lengths,         // [B]
    u64* __restrict__ hbuf,                  // [2][NCHK] chunks
    float* __restrict__ out)                 // ys[B][T][H], hT[B][H], cT[B][H] fp32
{
  __shared__ __align__(16) unsigned short h_lds[32 * HP];         // 33.3 KB
  __shared__ __align__(16) unsigned short piL[RNG * 6 * 16 * 32]; // 18.4 KB [slot][g][c][b]
  __shared__ __align__(16) float ps_lds[5 * 16 * 36];             // [gate][c][b pad]

  const int tid = threadIdx.x;
  const int lane = tid & 63;
  const int w = tid >> 6;          // wave = gate (0..4) for MFMA phase
  const int wg = blockIdx.x;
  const int ci0 = wg * 16;
  const int mc = lane & 15;
  const int kq = lane >> 4;

  // Ws B-fragments in registers: lane covers Ws row w*H + ci0 + mc
  short8 bfrag[16];
  {
    const float* wsrow = Ws + (size_t)(w * cH + ci0 + mc) * cH;
    #pragma unroll
    for (int kt = 0; kt < 16; kt++) {
      float4 f0 = *(const float4*)(wsrow + kt * 32 + kq * 8);
      float4 f1 = *(const float4*)(wsrow + kt * 32 + kq * 8 + 4);
      short8 pk;
      pk[0] = (short)f2bf(f0.x); pk[1] = (short)f2bf(f0.y);
      pk[2] = (short)f2bf(f0.z); pk[3] = (short)f2bf(f0.w);
      pk[4] = (short)f2bf(f1.x); pk[5] = (short)f2bf(f1.y);
      pk[6] = (short)f2bf(f1.z); pk[7] = (short)f2bf(f1.w);
      bfrag[kt] = pk;
    }
  }

  // Per-thread gate state in registers (fixed (b, colpair) ownership, tid<256)
  const int gb = tid & 31;         // batch row
  const int gcp = tid >> 5;        // local col-pair 0..7
  const int col0 = ci0 + 2 * gcp;
  float c0 = 0.f, c1 = 0.f, hp0 = 0.f, hp1 = 0.f;
  float bsv[5][2];
  int len_b = 0;
  if (tid < 256) {
    len_b = lengths[gb];
    #pragma unroll
    for (int g = 0; g < 5; g++) {
      bsv[g][0] = bs[g * cH + col0];
      bsv[g][1] = bs[g * cH + col0 + 1];
    }
    // bootstrap: publish own zero slice with seq=0 into slot 0
    __hip_atomic_store(hbuf + (size_t)gb * 256 + (ci0 >> 1) + gcp, 0ull,
                       __ATOMIC_RELAXED, __HIP_MEMORY_SCOPE_AGENT);
  }

  // pi ring prologue: t=0 -> slot0, t=1 -> slot1
  for (int s = 0; s < 2; s++) {
    const unsigned short* pit = pi + (size_t)s * cKI * cB;
    for (int j = tid; j < 384; j += THR) {
      int g = j >> 6, rem = j & 63, c = rem >> 2, q = rem & 3;
      uint4 v = *(const uint4*)(pit + ((size_t)g * cH + ci0 + c) * cB + q * 8);
      *(uint4*)(piL + s * 3072 + (g * 16 + c) * 32 + q * 8) = v;
    }
  }
  __syncthreads();

  const int nck = (tid < NCHK - (MAXK - 1) * THR) ? MAXK : MAXK - 1;  // 8192 = 25*320+192

  for (int t = 0; t < cT; t++) {
    // [P] pi global loads for step t+2 (in flight across the step)
    uint4 pv0, pv1;
    const bool pf = (t + 2) < cT;
    const int slot_w = (t + 2) % RNG;
    if (pf) {
      const unsigned short* pit = pi + (size_t)(t + 2) * cKI * cB;
      { int g = tid >> 6, rem = tid & 63, c = rem >> 2, q = rem & 3;
        pv0 = *(const uint4*)(pit + ((size_t)g * cH + ci0 + c) * cB + q * 8); }
      int j1 = tid + THR;
      if (j1 < 384) { int g = j1 >> 6, rem = j1 & 63, c = rem >> 2, q = rem & 3;
        pv1 = *(const uint4*)(pit + ((size_t)g * cH + ci0 + c) * cB + q * 8); }
    }

    // [A] poll + stage h(t): chunk valid when seq field == t
    {
      const u64* hslot = hbuf + (size_t)(t & 1) * NCHK;
      const unsigned int seqv = (unsigned int)t;
      bool got[MAXK];
      #pragma unroll
      for (int k = 0; k < MAXK; k++) got[k] = (k >= nck);
      int rem = nck;
      while (rem > 0) {
        #pragma unroll
        for (int k = 0; k < MAXK; k++) {
          if (!got[k]) {
            int idx = tid + k * THR;
            u64 v = __hip_atomic_load(hslot + idx, __ATOMIC_RELAXED, __HIP_MEMORY_SCOPE_AGENT);
            if ((unsigned int)(v >> 32) == seqv) {
              got[k] = true; rem--;
              *(unsigned int*)(h_lds + (idx >> 8) * HP + (idx & 255) * 2) = (unsigned int)v;
            }
          }
        }
      }
    }
    __syncthreads();   // S0: h_lds complete (drains in-flight stores too; overlapped)

    // [D] MFMA: wave w computes ps[:, gate w] : 32x16, K=512 (Ws from registers)
    f32x4 acc0 = (f32x4){0.f,0.f,0.f,0.f}, acc1 = (f32x4){0.f,0.f,0.f,0.f};
    #pragma unroll
    for (int kt = 0; kt < 16; kt++) {
      int kc = kt * 4 + kq;
      short8 a0 = *(const short8*)(h_lds + mc * HP + kc * 8);
      short8 a1 = *(const short8*)(h_lds + (16 + mc) * HP + kc * 8);
      acc0 = __builtin_amdgcn_mfma_f32_16x16x32_bf16(a0, bfrag[kt], acc0, 0, 0, 0);
      acc1 = __builtin_amdgcn_mfma_f32_16x16x32_bf16(a1, bfrag[kt], acc1, 0, 0, 0);
    }
    {
      int r0 = kq * 4;   // C layout: col=lane&15 (=c), rows=(lane>>4)*4+reg (=b)
      *(f32x4*)(ps_lds + (w * 16 + mc) * 36 + r0) = acc0;
      *(f32x4*)(ps_lds + (w * 16 + mc) * 36 + r0 + 16) = acc1;
    }
    // [E] pi ring write for t+2
    if (pf) {
      { int g = tid >> 6, rem2 = tid & 63, c = rem2 >> 2, q = rem2 & 3;
        *(uint4*)(piL + slot_w * 3072 + (g * 16 + c) * 32 + q * 8) = pv0; }
      int j1 = tid + THR;
      if (j1 < 384) { int g = j1 >> 6, rem2 = j1 & 63, c = rem2 >> 2, q = rem2 & 3;
        *(uint4*)(piL + slot_w * 3072 + (g * 16 + c) * 32 + q * 8) = pv1; }
    }
    __syncthreads();   // S1: ps + ring visible

    // [F] gates (256 threads, 2 cols each) + fused chunk publish
    if (tid < 256) {
      const unsigned short* pl = piL + (t % RNG) * 3072;
      const int c_a = 2 * gcp, c_b = 2 * gcp + 1;
      float ai0 = bf2f(pl[(0*16 + c_a)*32 + gb]) + ps_lds[(0*16 + c_a)*36 + gb] + bsv[0][0];
      float ai1 = bf2f(pl[(0*16 + c_b)*32 + gb]) + ps_lds[(0*16 + c_b)*36 + gb] + bsv[0][1];
      float af0 = bf2f(pl[(1*16 + c_a)*32 + gb]) + ps_lds[(1*16 + c_a)*36 + gb] + bsv[1][0];
      float af1 = bf2f(pl[(1*16 + c_b)*32 + gb]) + ps_lds[(1*16 + c_b)*36 + gb] + bsv[1][1];
      float ag0 = bf2f(pl[(2*16 + c_a)*32 + gb]) + ps_lds[(2*16 + c_a)*36 + gb] + bsv[2][0];
      float ag1 = bf2f(pl[(2*16 + c_b)*32 + gb]) + ps_lds[(2*16 + c_b)*36 + gb] + bsv[2][1];
      float ao0 = bf2f(pl[(3*16 + c_a)*32 + gb]) + ps_lds[(3*16 + c_a)*36 + gb] + bsv[3][0];
      float ao1 = bf2f(pl[(3*16 + c_b)*32 + gb]) + ps_lds[(3*16 + c_b)*36 + gb] + bsv[3][1];
      float ar0 = bf2f(pl[(4*16 + c_a)*32 + gb]) + ps_lds[(4*16 + c_a)*36 + gb] + bsv[4][0];
      float ar1 = bf2f(pl[(4*16 + c_b)*32 + gb]) + ps_lds[(4*16 + c_b)*36 + gb] + bsv[4][1];
      float p50 = bf2f(pl[(5*16 + c_a)*32 + gb]);
      float p51 = bf2f(pl[(5*16 + c_b)*32 + gb]);

      float cn0 = sigm(ai0) * tanh_f(ag0) + sigm(af0) * c0;
      float cn1 = sigm(ai1) * tanh_f(ag1) + sigm(af1) * c1;
      float ov0 = sigm(ao0) * tanh_f(cn0);
      float ov1 = sigm(ao1) * tanh_f(cn1);
      float r0g = sigm(ar0), r1g = sigm(ar1);
      ov0 = r0g * ov0 + (1.0f - r0g) * p50;
      ov1 = r1g * ov1 + (1.0f - r1g) * p51;

      bool m = (t < len_b);
      float hn0 = m ? ov0 : hp0;
      float hn1 = m ? ov1 : hp1;
      c0 = m ? cn0 : c0;
      c1 = m ? cn1 : c1;
      hp0 = hn0; hp1 = hn1;

      // publish own chunk for h(t+1)
      if (t + 1 < cT) {
        u64 pk = ((u64)(unsigned int)(t + 1) << 32)
               | ((u64)(unsigned int)f2bf(hn1) << 16) | (u64)(unsigned int)f2bf(hn0);
        u64* hd = hbuf + (size_t)((t + 1) & 1) * NCHK;
        __hip_atomic_store(hd + (size_t)gb * 256 + (ci0 >> 1) + gcp, pk,
                           __ATOMIC_RELAXED, __HIP_MEMORY_SCOPE_AGENT);
      }
      float2 yv; yv.x = m ? ov0 : 0.0f; yv.y = m ? ov1 : 0.0f;
      *(float2*)(out + ((size_t)gb * cT + t) * cH + col0) = yv;
      if (t == cT - 1) {
        float2 hv; hv.x = hn0; hv.y = hn1;
        *(float2*)(out + (size_t)cB * cT * cH + (size_t)gb * cH + col0) = hv;
      }
    }
  }

  // cT from register c state (own values, no sync needed)
  if (tid < 256) {
    float2 cv; cv.x = c0; cv.y = c1;
    *(float2*)(out + (size_t)cB * cT * cH + (size_t)cB * cH + (size_t)gb * cH + col0) = cv;
  }
}

extern "C" void kernel_launch(void* const* d_in, const int* in_sizes, int n_in,
                              void* d_out, int out_size, void* d_ws, size_t ws_size,
                              hipStream_t stream) {
  const float* x       = (const float*)d_in[0];
  const int* lengths   = (const int*)d_in[1];
  const float* Wi      = (const float*)d_in[2];
  const float* bi      = (const float*)d_in[3];
  const float* Ws      = (const float*)d_in[4];
  const float* bs      = (const float*)d_in[5];
  float* out = (float*)d_out;

  char* ws = (char*)d_ws;
  u64* hbuf = (u64*)(ws + 4096);                            // 2 slots x 8192 chunks = 128KB
  unsigned short* pi = (unsigned short*)(ws + (1 << 20));   // [512][3072][32] bf16

  dim3 grid1(cKI / 128, (cB * cT) / 128);
  gemm_pi<<<grid1, 256, 0, stream>>>(x, Wi, bi, pi);
  lstm_rec<<<NWG, THR, 0, stream>>>(pi, Ws, bs, lengths, hbuf, out);
}

// Round 9
// 2632.999 us; speedup vs baseline: 4.7014x; 4.7014x over previous
//
#include <hip/hip_runtime.h>
#include <stdint.h>

typedef __attribute__((ext_vector_type(8))) short short8;
typedef __attribute__((ext_vector_type(4))) float f32x4;
typedef unsigned long long u64;

constexpr int cB = 32, cT = 512, cD = 512, cH = 512;
constexpr int cKI = 6 * cH;   // 3072
constexpr int NWG = 32;
constexpr int THR = 320;
constexpr int LDW = 40;       // gemm LDS row pitch (shorts)
constexpr int HP  = 520;      // rec LDS row pitch (shorts); dword-stride 260 = 4 mod 32 (2-way on MFMA reads)
constexpr int RNG = 3;        // pi prefetch ring depth
constexpr int NCHK = 8192;    // chunks per h slot: 256 col-pairs x 32 b (cp-major)
constexpr int MAXK = 26;      // ceil(8192/320)

__device__ __forceinline__ float bf2f(unsigned short u) {
  union { unsigned int i; float f; } x; x.i = ((unsigned int)u) << 16; return x.f;
}
__device__ __forceinline__ unsigned short f2bf(float f) {
  union { float f; unsigned int i; } x; x.f = f;
  return (unsigned short)((x.i + 0x7fffu + ((x.i >> 16) & 1u)) >> 16);
}
__device__ __forceinline__ float sigm(float v) { return 1.0f / (1.0f + __expf(-v)); }
__device__ __forceinline__ float tanh_f(float v) { return 2.0f / (1.0f + __expf(-2.0f * v)) - 1.0f; }

// ---------------- Phase 1: pi[t][k][b] = x[b][t][:] . Wi[k][:] + bi[k] ----------------
__global__ __launch_bounds__(256) void gemm_pi(
    const float* __restrict__ x,    // [B][T][D] fp32
    const float* __restrict__ Wi,   // [6H][D] fp32
    const float* __restrict__ bi,   // [6H] fp32
    unsigned short* __restrict__ pi)// [T][6H][B] bf16
{
  __shared__ __align__(16) unsigned short Ai[128 * LDW];
  __shared__ __align__(16) unsigned short Bi[128 * LDW];

  const int tid = threadIdx.x;
  const int lane = tid & 63;
  const int w = tid >> 6;
  const int wm = w & 1, wn = w >> 1;
  const int k0 = blockIdx.x * 128;
  const int n0 = blockIdx.y * 128;   // n = t*32 + b

  f32x4 acc[4][4];
  #pragma unroll
  for (int i = 0; i < 4; i++)
    #pragma unroll
    for (int j = 0; j < 4; j++) acc[i][j] = (f32x4){0.f, 0.f, 0.f, 0.f};

  for (int kk = 0; kk < cD; kk += 32) {
    __syncthreads();
    #pragma unroll
    for (int it = 0; it < 4; it++) {
      int idx = tid + it * 256;
      int r = idx >> 3, ch = idx & 7;
      int na = n0 + r;
      int bb = na & 31, tt = na >> 5;
      float4 va = *(const float4*)(x + ((size_t)bb * cT + tt) * cD + kk + ch * 4);
      ushort4 pa; pa.x = f2bf(va.x); pa.y = f2bf(va.y); pa.z = f2bf(va.z); pa.w = f2bf(va.w);
      *(ushort4*)(Ai + r * LDW + ch * 4) = pa;
      float4 vb = *(const float4*)(Wi + (size_t)(k0 + r) * cD + kk + ch * 4);
      ushort4 pb; pb.x = f2bf(vb.x); pb.y = f2bf(vb.y); pb.z = f2bf(vb.z); pb.w = f2bf(vb.w);
      *(ushort4*)(Bi + r * LDW + ch * 4) = pb;
    }
    __syncthreads();

    short8 af[4], bfr[4];
    const int q = lane >> 4;
    #pragma unroll
    for (int mi = 0; mi < 4; mi++) {
      int m = wm * 64 + mi * 16 + (lane & 15);
      af[mi] = *(const short8*)(Ai + m * LDW + q * 8);
    }
    #pragma unroll
    for (int ni = 0; ni < 4; ni++) {
      int n = wn * 64 + ni * 16 + (lane & 15);
      bfr[ni] = *(const short8*)(Bi + n * LDW + q * 8);
    }
    #pragma unroll
    for (int mi = 0; mi < 4; mi++)
      #pragma unroll
      for (int ni = 0; ni < 4; ni++)
        acc[mi][ni] = __builtin_amdgcn_mfma_f32_16x16x32_bf16(af[mi], bfr[ni], acc[mi][ni], 0, 0, 0);
  }

  #pragma unroll
  for (int ni = 0; ni < 4; ni++) {
    int kl = wn * 64 + ni * 16 + (lane & 15);
    float bv = bi[k0 + kl];
    #pragma unroll
    for (int mi = 0; mi < 4; mi++) {
      int nl = wm * 64 + mi * 16 + (lane >> 4) * 4;
      int nb = n0 + nl;
      int b0 = nb & 31, tt = nb >> 5;
      f32x4 a = acc[mi][ni];
      unsigned short v0 = f2bf(a.x + bv), v1 = f2bf(a.y + bv);
      unsigned short v2 = f2bf(a.z + bv), v3 = f2bf(a.w + bv);
      uint2 pv; pv.x = (unsigned)v0 | ((unsigned)v1 << 16);
      pv.y = (unsigned)v2 | ((unsigned)v3 << 16);
      *(uint2*)(pi + ((size_t)tt * cKI + k0 + kl) * cB + b0) = pv;
    }
  }
}

// ---------------- Phase 2: persistent scan, dataflow chunk exchange (batched rounds) ----------------
// h exchanged as self-validating 8B chunks {seq:32 | h1:16 | h0:16}, cp-major layout
// (chunk idx = colpair*32 + b) so producer wave-stores are lane-coalesced.
// Consumer: rounds of batch-issued loads, then validate+stage. No barrier, no flags.
__global__ __launch_bounds__(THR, 1) void lstm_rec(
    const unsigned short* __restrict__ pi,   // [T][6H][B] bf16
    const float* __restrict__ Ws,            // [5H][H] fp32
    const float* __restrict__ bs,            // [5H] fp32
    const int* __restrict__ lengths,         // [B]
    u64* __restrict__ hbuf,                  // [2][NCHK] chunks
    float* __restrict__ out)                 // ys[B][T][H], hT[B][H], cT[B][H] fp32
{
  __shared__ __align__(16) unsigned short h_lds[32 * HP];         // 33.3 KB [b][col]
  __shared__ __align__(16) unsigned short piL[RNG * 6 * 16 * 32]; // 18.4 KB [slot][g][c][b]
  __shared__ __align__(16) float ps_lds[5 * 16 * 36];             // [gate][c][b pad]

  const int tid = threadIdx.x;
  const int lane = tid & 63;
  const int w = tid >> 6;          // wave = gate (0..4) for MFMA phase
  const int wg = blockIdx.x;
  const int ci0 = wg * 16;
  const int mc = lane & 15;
  const int kq = lane >> 4;

  // Ws B-fragments in registers: lane covers Ws row w*H + ci0 + mc
  short8 bfrag[16];
  {
    const float* wsrow = Ws + (size_t)(w * cH + ci0 + mc) * cH;
    #pragma unroll
    for (int kt = 0; kt < 16; kt++) {
      float4 f0 = *(const float4*)(wsrow + kt * 32 + kq * 8);
      float4 f1 = *(const float4*)(wsrow + kt * 32 + kq * 8 + 4);
      short8 pk;
      pk[0] = (short)f2bf(f0.x); pk[1] = (short)f2bf(f0.y);
      pk[2] = (short)f2bf(f0.z); pk[3] = (short)f2bf(f0.w);
      pk[4] = (short)f2bf(f1.x); pk[5] = (short)f2bf(f1.y);
      pk[6] = (short)f2bf(f1.z); pk[7] = (short)f2bf(f1.w);
      bfrag[kt] = pk;
    }
  }

  // Per-thread gate state (tid<256): b = tid&31 (lane-coalesced chunk stores), colpair = tid>>5
  const int gb = tid & 31;
  const int gcp = tid >> 5;
  const int col0 = ci0 + 2 * gcp;
  const int myck = (ci0 / 2 + gcp) * 32 + gb;   // cp-major chunk index
  float c0 = 0.f, c1 = 0.f, hp0 = 0.f, hp1 = 0.f;
  float bsv[5][2];
  int len_b = 0;
  if (tid < 256) {
    len_b = lengths[gb];
    #pragma unroll
    for (int g = 0; g < 5; g++) {
      bsv[g][0] = bs[g * cH + col0];
      bsv[g][1] = bs[g * cH + col0 + 1];
    }
    // bootstrap: publish own zero chunk with seq=0 into slot 0
    __hip_atomic_store(hbuf + myck, 0ull, __ATOMIC_RELAXED, __HIP_MEMORY_SCOPE_AGENT);
  }

  // pi ring prologue: t=0 -> slot0, t=1 -> slot1
  for (int s = 0; s < 2; s++) {
    const unsigned short* pit = pi + (size_t)s * cKI * cB;
    for (int j = tid; j < 384; j += THR) {
      int g = j >> 6, rem = j & 63, c = rem >> 2, q = rem & 3;
      uint4 v = *(const uint4*)(pit + ((size_t)g * cH + ci0 + c) * cB + q * 8);
      *(uint4*)(piL + s * 3072 + (g * 16 + c) * 32 + q * 8) = v;
    }
  }

  const int nck = (tid < NCHK - (MAXK - 1) * THR) ? MAXK : MAXK - 1;  // 8192 = 25*320+192

  for (int t = 0; t < cT; t++) {
    // [P] pi loads for step t+2 (fill staging-wait time; consumed at [E])
    uint4 pv0, pv1;
    const bool pf = (t + 2) < cT;
    const int slot_w = (t + 2) % RNG;
    if (pf) {
      const unsigned short* pit = pi + (size_t)(t + 2) * cKI * cB;
      { int g = tid >> 6, rem = tid & 63, c = rem >> 2, q = rem & 3;
        pv0 = *(const uint4*)(pit + ((size_t)g * cH + ci0 + c) * cB + q * 8); }
      int j1 = tid + THR;
      if (j1 < 384) { int g = j1 >> 6, rem = j1 & 63, c = rem >> 2, q = rem & 3;
        pv1 = *(const uint4*)(pit + ((size_t)g * cH + ci0 + c) * cB + q * 8); }
    }

    // [A] stage h(t): batched rounds. Round = issue ALL missing loads, then validate.
    {
      const u64* hslot = hbuf + (size_t)(t & 1) * NCHK;
      const unsigned int seqv = (unsigned int)t;
      unsigned int gotm = 0;
      int rem = nck;
      u64 v[MAXK];
      while (rem > 0) {
        #pragma unroll
        for (int k = 0; k < MAXK; k++)
          if (k < nck && !((gotm >> k) & 1u))
            v[k] = __hip_atomic_load(hslot + tid + k * THR, __ATOMIC_RELAXED, __HIP_MEMORY_SCOPE_AGENT);
        #pragma unroll
        for (int k = 0; k < MAXK; k++)
          if (k < nck && !((gotm >> k) & 1u)) {
            if ((unsigned int)(v[k] >> 32) == seqv) {
              gotm |= 1u << k; rem--;
              int idx = tid + k * THR;           // idx = cp*32 + b
              *(unsigned int*)(h_lds + (idx & 31) * HP + (idx >> 5) * 2) = (unsigned int)v[k];
            }
          }
      }
    }
    __syncthreads();   // S0: h_lds complete

    // [D] MFMA: wave w computes ps[:, gate w] : 32x16, K=512 (Ws from registers)
    f32x4 acc0 = (f32x4){0.f,0.f,0.f,0.f}, acc1 = (f32x4){0.f,0.f,0.f,0.f};
    #pragma unroll
    for (int kt = 0; kt < 16; kt++) {
      int kc = kt * 4 + kq;
      short8 a0 = *(const short8*)(h_lds + mc * HP + kc * 8);
      short8 a1 = *(const short8*)(h_lds + (16 + mc) * HP + kc * 8);
      acc0 = __builtin_amdgcn_mfma_f32_16x16x32_bf16(a0, bfrag[kt], acc0, 0, 0, 0);
      acc1 = __builtin_amdgcn_mfma_f32_16x16x32_bf16(a1, bfrag[kt], acc1, 0, 0, 0);
    }
    {
      int r0 = kq * 4;   // C layout: col=lane&15 (=c), rows=(lane>>4)*4+reg (=b)
      *(f32x4*)(ps_lds + (w * 16 + mc) * 36 + r0) = acc0;
      *(f32x4*)(ps_lds + (w * 16 + mc) * 36 + r0 + 16) = acc1;
    }
    // [E] pi ring write for t+2
    if (pf) {
      { int g = tid >> 6, rem2 = tid & 63, c = rem2 >> 2, q = rem2 & 3;
        *(uint4*)(piL + slot_w * 3072 + (g * 16 + c) * 32 + q * 8) = pv0; }
      int j1 = tid + THR;
      if (j1 < 384) { int g = j1 >> 6, rem2 = j1 & 63, c = rem2 >> 2, q = rem2 & 3;
        *(uint4*)(piL + slot_w * 3072 + (g * 16 + c) * 32 + q * 8) = pv1; }
    }
    __syncthreads();   // S1: ps + ring visible

    // [F] gates (256 threads, 2 cols each) + immediate coalesced chunk publish
    if (tid < 256) {
      const unsigned short* pl = piL + (t % RNG) * 3072;
      const int c_a = 2 * gcp, c_b = 2 * gcp + 1;
      float ai0 = bf2f(pl[(0*16 + c_a)*32 + gb]) + ps_lds[(0*16 + c_a)*36 + gb] + bsv[0][0];
      float ai1 = bf2f(pl[(0*16 + c_b)*32 + gb]) + ps_lds[(0*16 + c_b)*36 + gb] + bsv[0][1];
      float af0 = bf2f(pl[(1*16 + c_a)*32 + gb]) + ps_lds[(1*16 + c_a)*36 + gb] + bsv[1][0];
      float af1 = bf2f(pl[(1*16 + c_b)*32 + gb]) + ps_lds[(1*16 + c_b)*36 + gb] + bsv[1][1];
      float ag0 = bf2f(pl[(2*16 + c_a)*32 + gb]) + ps_lds[(2*16 + c_a)*36 + gb] + bsv[2][0];
      float ag1 = bf2f(pl[(2*16 + c_b)*32 + gb]) + ps_lds[(2*16 + c_b)*36 + gb] + bsv[2][1];
      float ao0 = bf2f(pl[(3*16 + c_a)*32 + gb]) + ps_lds[(3*16 + c_a)*36 + gb] + bsv[3][0];
      float ao1 = bf2f(pl[(3*16 + c_b)*32 + gb]) + ps_lds[(3*16 + c_b)*36 + gb] + bsv[3][1];
      float ar0 = bf2f(pl[(4*16 + c_a)*32 + gb]) + ps_lds[(4*16 + c_a)*36 + gb] + bsv[4][0];
      float ar1 = bf2f(pl[(4*16 + c_b)*32 + gb]) + ps_lds[(4*16 + c_b)*36 + gb] + bsv[4][1];
      float p50 = bf2f(pl[(5*16 + c_a)*32 + gb]);
      float p51 = bf2f(pl[(5*16 + c_b)*32 + gb]);

      float cn0 = sigm(ai0) * tanh_f(ag0) + sigm(af0) * c0;
      float cn1 = sigm(ai1) * tanh_f(ag1) + sigm(af1) * c1;
      float ov0 = sigm(ao0) * tanh_f(cn0);
      float ov1 = sigm(ao1) * tanh_f(cn1);
      float r0g = sigm(ar0), r1g = sigm(ar1);
      ov0 = r0g * ov0 + (1.0f - r0g) * p50;
      ov1 = r1g * ov1 + (1.0f - r1g) * p51;

      bool m = (t < len_b);
      float hn0 = m ? ov0 : hp0;
      float hn1 = m ? ov1 : hp1;
      c0 = m ? cn0 : c0;
      c1 = m ? cn1 : c1;
      hp0 = hn0; hp1 = hn1;

      // publish h(t+1) chunk FIRST (critical path), ys stores after
      if (t + 1 < cT) {
        u64 pk = ((u64)(unsigned int)(t + 1) << 32)
               | ((u64)(unsigned int)f2bf(hn1) << 16) | (u64)(unsigned int)f2bf(hn0);
        __hip_atomic_store(hbuf + (size_t)((t + 1) & 1) * NCHK + myck, pk,
                           __ATOMIC_RELAXED, __HIP_MEMORY_SCOPE_AGENT);
      }
      float2 yv; yv.x = m ? ov0 : 0.0f; yv.y = m ? ov1 : 0.0f;
      *(float2*)(out + ((size_t)gb * cT + t) * cH + col0) = yv;
      if (t == cT - 1) {
        float2 hv; hv.x = hn0; hv.y = hn1;
        *(float2*)(out + (size_t)cB * cT * cH + (size_t)gb * cH + col0) = hv;
      }
    }
  }

  // cT from register c state
  if (tid < 256) {
    float2 cv; cv.x = c0; cv.y = c1;
    *(float2*)(out + (size_t)cB * cT * cH + (size_t)cB * cH + (size_t)gb * cH + col0) = cv;
  }
}

extern "C" void kernel_launch(void* const* d_in, const int* in_sizes, int n_in,
                              void* d_out, int out_size, void* d_ws, size_t ws_size,
                              hipStream_t stream) {
  const float* x       = (const float*)d_in[0];
  const int* lengths   = (const int*)d_in[1];
  const float* Wi      = (const float*)d_in[2];
  const float* bi      = (const float*)d_in[3];
  const float* Ws      = (const float*)d_in[4];
  const float* bs      = (const float*)d_in[5];
  float* out = (float*)d_out;

  char* ws = (char*)d_ws;
  u64* hbuf = (u64*)(ws + 4096);                            // 2 slots x 8192 chunks = 128KB
  unsigned short* pi = (unsigned short*)(ws + (1 << 20));   // [512][3072][32] bf16

  dim3 grid1(cKI / 128, (cB * cT) / 128);
  gemm_pi<<<grid1, 256, 0, stream>>>(x, Wi, bi, pi);
  lstm_rec<<<NWG, THR, 0, stream>>>(pi, Ws, bs, lengths, hbuf, out);
}